// Round 1
// baseline (484.100 us; speedup 1.0000x reference)
//
#include <hip/hip_runtime.h>

// Fp8Padding: gather rows of inp [37834, 2048] f32 into padded out [37888, 2048] f32.
// Segments (static): M = {4091,8177,2045,4093,6133,1021,4085,8189}
//                    P = {4096,8192,2048,4096,6144,1024,4096,8192}
// Pure memory-bound multi-segment copy; pad rows zero-filled.

constexpr int HIDDEN   = 2048;
constexpr int HIDDEN4  = HIDDEN / 4;   // 512 float4 per row
constexpr int NSEG     = 8;
constexpr int TOTAL_OUT = 37888;

// Padded destination row prefix sums (dst start of each segment, +end)
__device__ __constant__ int d_dst[NSEG + 1] =
    {0, 4096, 12288, 14336, 18432, 24576, 25600, 29696, 37888};
// Unpadded source row prefix sums (src start of each segment)
__device__ __constant__ int d_srcs[NSEG] =
    {0, 4091, 12268, 14313, 18406, 24539, 25560, 29645};
// Valid row count per segment
__device__ __constant__ int d_m[NSEG] =
    {4091, 8177, 2045, 4093, 6133, 1021, 4085, 8189};

__global__ __launch_bounds__(256) void fp8_pad_copy(
    const float* __restrict__ in, float* __restrict__ out) {
    const int row = blockIdx.x;   // one block per output row

    // Find which segment this output row belongs to (7 compares, wave-uniform).
    int seg = 0;
#pragma unroll
    for (int s = 1; s < NSEG; ++s) seg += (row >= d_dst[s]) ? 1 : 0;

    const int local = row - d_dst[seg];
    const int srow  = (local < d_m[seg]) ? (d_srcs[seg] + local) : -1;

    const float4* __restrict__ in4  = reinterpret_cast<const float4*>(in);
    float4* __restrict__       out4 = reinterpret_cast<float4*>(out);
    const long ro = (long)row * HIDDEN4;

    if (srow >= 0) {
        const long si = (long)srow * HIDDEN4;
#pragma unroll
        for (int t = threadIdx.x; t < HIDDEN4; t += 256) {
            out4[ro + t] = in4[si + t];
        }
    } else {
        const float4 z = make_float4(0.f, 0.f, 0.f, 0.f);
#pragma unroll
        for (int t = threadIdx.x; t < HIDDEN4; t += 256) {
            out4[ro + t] = z;
        }
    }
}

extern "C" void kernel_launch(void* const* d_in, const int* in_sizes, int n_in,
                              void* d_out, int out_size, void* d_ws, size_t ws_size,
                              hipStream_t stream) {
    const float* in = reinterpret_cast<const float*>(d_in[0]);
    float* out      = reinterpret_cast<float*>(d_out);
    fp8_pad_copy<<<TOTAL_OUT, 256, 0, stream>>>(in, out);
}

// Round 2
// 483.157 us; speedup vs baseline: 1.0020x; 1.0020x over previous
//
#include <hip/hip_runtime.h>

// Fp8Padding: gather rows of inp [37834, 2048] f32 into padded out [37888, 2048] f32.
// Flat streaming copy in float4 units; segment found by 7-compare select chain
// on compile-time constants. Pad elements (54 rows) get zeros.
//
// TOTAL_OUT4 = 37888*512 = 19,398,656 = 9472 blocks * 256 threads * 8 items
// -> exact cover, no tail, 8 independent 16B loads in flight per thread.

typedef float fvec4 __attribute__((ext_vector_type(4)));

constexpr int NSEG = 8;
// Prefix sums in float4 units (row * 512)
constexpr int DST4[NSEG + 1] = {0, 2097152, 6291456, 7340032, 9437184,
                                12582912, 13107200, 15204352, 19398656};
constexpr int SRC4[NSEG] = {0, 2094592, 6281216, 7328256,
                            9423872, 12563968, 13086720, 15178240};
constexpr int MLEN4[NSEG] = {2094592, 4186624, 1047040, 2095616,
                             3140096, 522752, 2091520, 4192768};

constexpr int BLOCKS = 9472;
constexpr int TPB = 256;
constexpr int K = 8;
constexpr int STRIDE = BLOCKS * TPB;  // 2,424,832

__global__ __launch_bounds__(TPB) void fp8_pad_copy(const float* __restrict__ in,
                                                    float* __restrict__ out) {
    const fvec4* __restrict__ in4 = reinterpret_cast<const fvec4*>(in);
    fvec4* __restrict__ out4 = reinterpret_cast<fvec4*>(out);
    const int tid = blockIdx.x * TPB + threadIdx.x;

    fvec4 vals[K];
#pragma unroll
    for (int k = 0; k < K; ++k) {
        const int i = tid + k * STRIDE;
        // Segment select chain: all operands are immediates after unroll.
        int dstb = DST4[0], srcb = SRC4[0], mlen = MLEN4[0];
#pragma unroll
        for (int s = 1; s < NSEG; ++s) {
            const bool ge = i >= DST4[s];
            dstb = ge ? DST4[s] : dstb;
            srcb = ge ? SRC4[s] : srcb;
            mlen = ge ? MLEN4[s] : mlen;
        }
        const int local = i - dstb;
        fvec4 v = {0.f, 0.f, 0.f, 0.f};
        if (local < mlen) {
            v = __builtin_nontemporal_load(&in4[srcb + local]);
        }
        vals[k] = v;
    }
#pragma unroll
    for (int k = 0; k < K; ++k) {
        const int i = tid + k * STRIDE;
        __builtin_nontemporal_store(vals[k], &out4[i]);
    }
}

extern "C" void kernel_launch(void* const* d_in, const int* in_sizes, int n_in,
                              void* d_out, int out_size, void* d_ws, size_t ws_size,
                              hipStream_t stream) {
    const float* in = reinterpret_cast<const float*>(d_in[0]);
    float* out = reinterpret_cast<float*>(d_out);
    fp8_pad_copy<<<BLOCKS, TPB, 0, stream>>>(in, out);
}